// Round 15
// baseline (212.008 us; speedup 1.0000x reference)
//
#include <hip/hip_runtime.h>
#include <math.h>

typedef unsigned short ushort_t;
typedef __attribute__((ext_vector_type(8))) __bf16 bf16x8;
typedef __attribute__((ext_vector_type(4))) float floatx4;

#define B_    256
#define I_    1152
#define J_    10
#define DIN_  8
#define DOUT_ 16
#define K_    (I_*DIN_)     // 9216
#define N_    (J_*DOUT_)    // 160
#define WPS   16            // waves per block = in-block split-K
#define KCHUNK (K_/WPS)     // 576 (72 i's per wave)
#define KSTEPS (KCHUNK/32)  // 18

static __device__ __forceinline__ ushort_t f2bf(float f) {
    unsigned int u = __float_as_uint(f);
    u += 0x7fffu + ((u >> 16) & 1u);     // RNE
    return (ushort_t)(u >> 16);
}
static __device__ __forceinline__ float bf2f(ushort_t h) {
    return __uint_as_float(((unsigned int)h) << 16);
}

// ---------------------------------------------------------------------------
// Fully-fused routing iteration: one block per (mb,nt) output tile does
//   softmax(blog) -> s-GEMM (in-block split-K=16) -> reduce+squash ->
//   in-block b-update GEMM -> atomicAdd partial logits into blog.
// No cross-block sync of any kind (atomic += order is irrelevant for fp32 sums;
// dispatch boundaries order iterations). All GEMM products fp32-equivalent via
// Dekker hi/lo bf16 splits (3 MFMAs per product).
// iter==0: c = 0.1f exactly (softmax of zero logits) — blog never read.
// iter==2: emit s_out, skip b-update.
// ---------------------------------------------------------------------------
__global__ __launch_bounds__(1024)
void capsule_iter_kernel(const float* __restrict__ x, const float* __restrict__ W,
                         float* __restrict__ blog, float* __restrict__ s_out,
                         const int iter)
{
    const int tid  = threadIdx.x;          // 0..1023
    const int tile = blockIdx.x;           // 0..159
    const int lane = tid & 63;
    const int w    = tid >> 6;             // wave = k-split 0..15
    const int mb   = tile / J_;
    const int nt   = tile - mb * J_;
    const int b0   = mb * 16;
    const int r    = lane & 15, q = lane >> 4;

    __shared__ float   c_lds[I_];          // c[i][nt] only: 4.6 KB
    __shared__ floatx4 part[WPS * 64];     // 16 KB partials
    __shared__ float   s_lds[16 * 16];     // squashed s tile [b_local][o]

    if (iter > 0) {
        for (int r2 = tid; r2 < I_; r2 += 1024) {
            const float* br = blog + (size_t)r2 * J_;
            float bv[J_];
            float mx = -1e30f;
            #pragma unroll
            for (int j = 0; j < J_; ++j) { bv[j] = br[j]; mx = fmaxf(mx, bv[j]); }
            float sum = 0.f;
            #pragma unroll
            for (int j = 0; j < J_; ++j) { bv[j] = __expf(bv[j] - mx); sum += bv[j]; }
            c_lds[r2] = bv[nt] / sum;
        }
        __syncthreads();
    }

    // ---- s-GEMM: per-wave k-chunk, A = x (Dekker), B = c*W (Dekker) ----
    {
        const float* ap = x + (size_t)(mb * 16 + r) * K_ + w * KCHUNK + 8 * q;
        // B row (j=nt, o=r); k-frag covers i = w*72 + 4s + q, d=0..7
        const float* wp = W + (((size_t)(w * 72 + q) * J_ + nt) * DOUT_ + r) * DIN_;
        floatx4 acc = {0.f, 0.f, 0.f, 0.f};
        #pragma unroll
        for (int s = 0; s < KSTEPS; ++s) {
            float4 xa0 = *(const float4*)(ap + s * 32);
            float4 xa1 = *(const float4*)(ap + s * 32 + 4);
            float4 w0  = *(const float4*)(wp + (size_t)s * 4 * J_ * DOUT_ * DIN_);
            float4 w1  = *(const float4*)(wp + (size_t)s * 4 * J_ * DOUT_ * DIN_ + 4);
            float cs   = (iter == 0) ? 0.1f : c_lds[w * 72 + 4 * s + q];
            float xv[8]  = {xa0.x, xa0.y, xa0.z, xa0.w, xa1.x, xa1.y, xa1.z, xa1.w};
            float wvv[8] = {w0.x, w0.y, w0.z, w0.w, w1.x, w1.y, w1.z, w1.w};
            bf16x8 ah, al, bh, bl;
            #pragma unroll
            for (int e = 0; e < 8; ++e) {
                float xe = xv[e];
                __bf16 h = (__bf16)xe;
                ah[e] = h;
                al[e] = (__bf16)(xe - (float)h);
                float pe = wvv[e] * cs;
                __bf16 g = (__bf16)pe;
                bh[e] = g;
                bl[e] = (__bf16)(pe - (float)g);
            }
            acc = __builtin_amdgcn_mfma_f32_16x16x32_bf16(ah, bh, acc, 0, 0, 0);
            acc = __builtin_amdgcn_mfma_f32_16x16x32_bf16(al, bh, acc, 0, 0, 0);
            acc = __builtin_amdgcn_mfma_f32_16x16x32_bf16(ah, bl, acc, 0, 0, 0);
        }
        part[w * 64 + lane] = acc;
    }
    __syncthreads();

    // ---- reduce 16 partials + squash; stash s tile in LDS (threads 0..255) ----
    if (tid < 256) {
        const int b_local = tid >> 4;                  // 0..15 (M row)
        const int o       = tid & 15;                  // 0..15 (N col)
        const int lane_c  = ((b_local >> 2) << 4) | o; // C/D: col=lane&15, row=quad*4+reg
        const int reg     = b_local & 3;
        float v = 0.f;
        #pragma unroll
        for (int u = 0; u < WPS; ++u)
            v += part[u * 64 + lane_c][reg];
        float sq = v * v;
        #pragma unroll
        for (int off = 1; off < 16; off <<= 1)
            sq += __shfl_xor(sq, off, 16);
        float l2 = sqrtf(sq);
        float val = v * (l2 / (1.f + sq));
        if (iter == 2)
            s_out[(size_t)(b0 + b_local) * N_ + nt * 16 + o] = val;
        else
            s_lds[b_local * 16 + o] = val;
    }

    if (iter == 2) return;
    __syncthreads();

    // ---- in-block b-update: Delta_blog[i,nt] = sum_{b in mb,o,d} W.x.s ----
    // G-GEMM: A[m=r][k=8q+e] = x[b0+8q+e][mt*16+r] (k>=16 zero-padded),
    // B[n=r][k=8q+e] = s_lds[8q+e][r]; 3 MFMAs (hi/lo) => fp32-equivalent.
    // Epilogue contracts with fp32 W, 32-lane shfl, atomicAdd into blog
    // (16 contending blocks per (i,nt); fp32 sum order irrelevant).
    {
        bf16x8 bh, bl;
        #pragma unroll
        for (int e = 0; e < 8; ++e) { bh[e] = (__bf16)0.f; bl[e] = (__bf16)0.f; }
        if (q < 2) {
            #pragma unroll
            for (int e = 0; e < 8; ++e) {
                float sv = s_lds[(8 * q + e) * 16 + r];
                __bf16 h = (__bf16)sv;
                bh[e] = h;
                bl[e] = (__bf16)(sv - (float)h);
            }
        }
        for (int mtl = 0; mtl < 36; ++mtl) {
            const int mt = w * 36 + mtl;               // 0..575
            bf16x8 ah, al;
            #pragma unroll
            for (int e = 0; e < 8; ++e) { ah[e] = (__bf16)0.f; al[e] = (__bf16)0.f; }
            if (q < 2) {
                const float* xp = x + (size_t)(b0 + 8 * q) * K_ + mt * 16 + r;
                #pragma unroll
                for (int e = 0; e < 8; ++e) {
                    float v = xp[(size_t)e * K_];      // quarter-wave-coalesced 64B
                    __bf16 h = (__bf16)v;
                    ah[e] = h;
                    al[e] = (__bf16)(v - (float)h);
                }
            }
            floatx4 accd = {0.f, 0.f, 0.f, 0.f};
            accd = __builtin_amdgcn_mfma_f32_16x16x32_bf16(ah, bh, accd, 0, 0, 0);
            accd = __builtin_amdgcn_mfma_f32_16x16x32_bf16(al, bh, accd, 0, 0, 0);
            accd = __builtin_amdgcn_mfma_f32_16x16x32_bf16(ah, bl, accd, 0, 0, 0);
            // rows q*4+reg -> i = mt*2 + (q>>1), d = (q&1)*4 + reg; col -> o
            const int i  = mt * 2 + (q >> 1);
            const int d0 = (q & 1) * 4;
            const int o  = lane & 15;
            const float4 w4 = *(const float4*)(W +
                ((((size_t)i * J_ + nt) * DOUT_ + o) * DIN_ + d0));
            float val = accd[0] * w4.x + accd[1] * w4.y
                      + accd[2] * w4.z + accd[3] * w4.w;
            #pragma unroll
            for (int off = 1; off < 32; off <<= 1)
                val += __shfl_xor(val, off, 32);
            if ((lane & 31) == 0)
                atomicAdd(blog + (size_t)(mt * 2 + (lane >> 5)) * J_ + nt, val);
        }
    }
}

// ---------------------------------------------------------------------------
extern "C" void kernel_launch(void* const* d_in, const int* in_sizes, int n_in,
                              void* d_out, int out_size, void* d_ws, size_t ws_size,
                              hipStream_t stream)
{
    const float* x = (const float*)d_in[0];   // [B, I, DIN]
    const float* W = (const float*)d_in[1];   // [I, J, DOUT, DIN]
    float* s_out = (float*)d_out;             // [B, J, DOUT]
    float* blog  = (float*)d_ws;              // 46,080 B — only workspace use

    hipMemsetAsync(blog, 0, (size_t)I_ * J_ * sizeof(float), stream);
    for (int it = 0; it < 3; ++it)
        capsule_iter_kernel<<<160, 1024, 0, stream>>>(x, W, blog, s_out, it);
}

// Round 16
// 160.635 us; speedup vs baseline: 1.3198x; 1.3198x over previous
//
#include <hip/hip_runtime.h>
#include <math.h>

typedef unsigned short ushort_t;
typedef __attribute__((ext_vector_type(8))) __bf16 bf16x8;
typedef __attribute__((ext_vector_type(4))) float floatx4;

#define B_    256
#define I_    1152
#define J_    10
#define DIN_  8
#define DOUT_ 16
#define K_    (I_*DIN_)     // 9216
#define N_    (J_*DOUT_)    // 160
#define WPS   16            // waves per block = in-block split-K
#define KCHUNK (K_/WPS)     // 576 (72 i's per wave)
#define KSTEPS (KCHUNK/32)  // 18

static __device__ __forceinline__ ushort_t f2bf(float f) {
    unsigned int u = __float_as_uint(f);
    u += 0x7fffu + ((u >> 16) & 1u);     // RNE
    return (ushort_t)(u >> 16);
}
static __device__ __forceinline__ float bf2f(ushort_t h) {
    return __uint_as_float(((unsigned int)h) << 16);
}

// ---------------------------------------------------------------------------
// Fused s-GEMM + in-block split-K reduce + squash (round-12 structure).
// 160 blocks x 1024 thr (16 waves; wave w = k-chunk w). Dekker hi/lo on both
// operands (3 MFMAs) => fp32-equivalent. __syncthreads only.
// Round-16 changes: (a) XCD-rectangle tile swizzle — blk&7 selects a 4-mb x
// 5-nt rectangle so each XCD's L2 holds a 5.3 MB working set instead of ~15MB;
// (b) explicit 1-step load prefetch in the K-loop (VGPR was 32 — compiler
// issued loads just-in-time; prefetch hides the ~600cyc L2/L3 miss latency).
// iter==0: c = 0.1f exactly (softmax of zero logits) — blog never read.
// iter<2: emit Sbt hi/lo (bupd inputs). iter==2: emit s_out only.
// ---------------------------------------------------------------------------
__global__ __launch_bounds__(1024)
void gemm_s_fused_kernel(const float* __restrict__ x, const float* __restrict__ W,
                         const float* __restrict__ blog, float* __restrict__ s_out,
                         ushort_t* __restrict__ Sbt_hi, ushort_t* __restrict__ Sbt_lo,
                         const int iter)
{
    const int tid  = threadIdx.x;          // 0..1023
    const int blk  = blockIdx.x;           // 0..159
    // XCD-rectangle swizzle (XCD = blk&7 heuristic; perf-only, correctness-free)
    const int xcd  = blk & 7;
    const int sl   = blk >> 3;             // 0..19
    const int mb   = (xcd >> 1) * 4 + (sl & 3);    // 0..15
    const int nt   = (xcd & 1) * 5 + (sl >> 2);    // 0..9
    const int lane = tid & 63;
    const int w    = tid >> 6;             // wave = k-split 0..15

    __shared__ float   c_lds[I_];          // c[i][nt] only: 4.6 KB
    __shared__ floatx4 part[WPS * 64];     // 16 KB partials

    if (iter > 0) {
        for (int r2 = tid; r2 < I_; r2 += 1024) {
            const float* br = blog + (size_t)r2 * J_;
            float bv[J_];
            float mx = -1e30f;
            #pragma unroll
            for (int j = 0; j < J_; ++j) { bv[j] = br[j]; mx = fmaxf(mx, bv[j]); }
            float sum = 0.f;
            #pragma unroll
            for (int j = 0; j < J_; ++j) { bv[j] = __expf(bv[j] - mx); sum += bv[j]; }
            c_lds[r2] = bv[nt] / sum;
        }
        __syncthreads();
    }

    {
        const int r = lane & 15, q = lane >> 4;
        const float* ap = x + (size_t)(mb * 16 + r) * K_ + w * KCHUNK + 8 * q;
        // B row (j=nt, o=r); k-frag covers i = w*72 + 4s + q, d=0..7
        const float* wp = W + (((size_t)(w * 72 + q) * J_ + nt) * DOUT_ + r) * DIN_;
        const size_t wstep = (size_t)4 * J_ * DOUT_ * DIN_;
        floatx4 acc = {0.f, 0.f, 0.f, 0.f};

        float4 xa0 = *(const float4*)(ap);
        float4 xa1 = *(const float4*)(ap + 4);
        float4 w0  = *(const float4*)(wp);
        float4 w1  = *(const float4*)(wp + 4);
        #pragma unroll
        for (int s = 0; s < KSTEPS; ++s) {
            float4 nxa0, nxa1, nw0, nw1;
            if (s + 1 < KSTEPS) {            // prefetch next step before compute
                nxa0 = *(const float4*)(ap + (s + 1) * 32);
                nxa1 = *(const float4*)(ap + (s + 1) * 32 + 4);
                nw0  = *(const float4*)(wp + (s + 1) * wstep);
                nw1  = *(const float4*)(wp + (s + 1) * wstep + 4);
            }
            float cs   = (iter == 0) ? 0.1f : c_lds[w * 72 + 4 * s + q];
            float xv[8]  = {xa0.x, xa0.y, xa0.z, xa0.w, xa1.x, xa1.y, xa1.z, xa1.w};
            float wvv[8] = {w0.x, w0.y, w0.z, w0.w, w1.x, w1.y, w1.z, w1.w};
            bf16x8 ah, al, bh, bl;
            #pragma unroll
            for (int e = 0; e < 8; ++e) {
                float xe = xv[e];
                __bf16 h = (__bf16)xe;
                ah[e] = h;
                al[e] = (__bf16)(xe - (float)h);
                float pe = wvv[e] * cs;
                __bf16 g = (__bf16)pe;
                bh[e] = g;
                bl[e] = (__bf16)(pe - (float)g);
            }
            acc = __builtin_amdgcn_mfma_f32_16x16x32_bf16(ah, bh, acc, 0, 0, 0);
            acc = __builtin_amdgcn_mfma_f32_16x16x32_bf16(al, bh, acc, 0, 0, 0);
            acc = __builtin_amdgcn_mfma_f32_16x16x32_bf16(ah, bl, acc, 0, 0, 0);
            if (s + 1 < KSTEPS) { xa0 = nxa0; xa1 = nxa1; w0 = nw0; w1 = nw1; }
        }
        part[w * 64 + lane] = acc;
    }
    __syncthreads();

    // ---- reduce 16 partials + squash + emit (threads 0..255) ----
    if (tid < 256) {
        const int b_local = tid >> 4;                  // 0..15 (M row)
        const int o       = tid & 15;                  // 0..15 (N col)
        const int lane_c  = ((b_local >> 2) << 4) | o; // C/D: col=lane&15, row=quad*4+reg
        const int reg     = b_local & 3;
        float v = 0.f;
        #pragma unroll
        for (int u = 0; u < WPS; ++u)
            v += part[u * 64 + lane_c][reg];
        float sq = v * v;
        #pragma unroll
        for (int off = 1; off < 16; off <<= 1)
            sq += __shfl_xor(sq, off, 16);
        float l2 = sqrtf(sq);
        float val = v * (l2 / (1.f + sq));
        const int b  = mb * 16 + b_local;
        const int jo = nt * 16 + o;
        if (iter == 2) {
            s_out[(size_t)b * N_ + jo] = val;
        } else {
            ushort_t hi = f2bf(val);
            Sbt_hi[(size_t)jo * B_ + b] = hi;
            Sbt_lo[(size_t)jo * B_ + b] = f2bf(val - bf2f(hi));
        }
    }
}

// ---------------------------------------------------------------------------
// b-update GEMM: T2 = X^T @ S' (M=9216 N=160 K=256). Each wave: one mt and
// TWO j's (A-side x loads + Dekker split shared). A read directly from fp32 x
// (quarter-wave-coalesced 64B lines) with 1-step prefetch; B from Sbt hi/lo.
// 3 MFMAs per j per step => fp32-equivalent. Epilogue contracts with fp32 W;
// unique (i,j) writer per half-wave. first!=0: blog = val.
// ---------------------------------------------------------------------------
__global__ __launch_bounds__(256)
void gemm_bupd_kernel(const float* __restrict__ x,
                      const ushort_t* __restrict__ Sbt_hi, const ushort_t* __restrict__ Sbt_lo,
                      const float* __restrict__ W, float* __restrict__ blog,
                      const int first)
{
    int wv   = blockIdx.x * 4 + (threadIdx.x >> 6);   // 0..2879
    int lane = threadIdx.x & 63;
    int mt = wv / 5;                                  // 0..575
    int jp = wv - mt * 5;                             // j-pair: j0=2jp, j1=2jp+1
    int j0 = jp * 2, j1 = jp * 2 + 1;
    int r = lane & 15, q = lane >> 4;
    const float* xp = x + (size_t)(8 * q) * K_ + (mt * 16 + r);   // + (s*32+e)*K_
    size_t b0off = (size_t)(j0 * 16 + r) * B_ + 8 * q;
    size_t b1off = (size_t)(j1 * 16 + r) * B_ + 8 * q;
    floatx4 acc0 = {0.f, 0.f, 0.f, 0.f};
    floatx4 acc1 = {0.f, 0.f, 0.f, 0.f};

    float xcur[8], xnxt[8];
    #pragma unroll
    for (int e = 0; e < 8; ++e) xcur[e] = xp[(size_t)e * K_];
    #pragma unroll
    for (int s = 0; s < B_ / 32; ++s) {
        if (s + 1 < B_ / 32) {               // prefetch next step's x column slice
            #pragma unroll
            for (int e = 0; e < 8; ++e)
                xnxt[e] = xp[(size_t)((s + 1) * 32 + e) * K_];
        }
        bf16x8 ah, al;
        #pragma unroll
        for (int e = 0; e < 8; ++e) {
            float v = xcur[e];
            __bf16 h = (__bf16)v;
            ah[e] = h;
            al[e] = (__bf16)(v - (float)h);
        }
        bf16x8 bh0 = *(const bf16x8*)(Sbt_hi + b0off + s * 32);
        bf16x8 bl0 = *(const bf16x8*)(Sbt_lo + b0off + s * 32);
        bf16x8 bh1 = *(const bf16x8*)(Sbt_hi + b1off + s * 32);
        bf16x8 bl1 = *(const bf16x8*)(Sbt_lo + b1off + s * 32);
        acc0 = __builtin_amdgcn_mfma_f32_16x16x32_bf16(ah, bh0, acc0, 0, 0, 0);
        acc0 = __builtin_amdgcn_mfma_f32_16x16x32_bf16(al, bh0, acc0, 0, 0, 0);
        acc0 = __builtin_amdgcn_mfma_f32_16x16x32_bf16(ah, bl0, acc0, 0, 0, 0);
        acc1 = __builtin_amdgcn_mfma_f32_16x16x32_bf16(ah, bh1, acc1, 0, 0, 0);
        acc1 = __builtin_amdgcn_mfma_f32_16x16x32_bf16(al, bh1, acc1, 0, 0, 0);
        acc1 = __builtin_amdgcn_mfma_f32_16x16x32_bf16(ah, bl1, acc1, 0, 0, 0);
        #pragma unroll
        for (int e = 0; e < 8; ++e) xcur[e] = xnxt[e];
    }
    // rows q*4+reg -> i = mt*2 + (q>>1), d = (q&1)*4 + reg; col -> o = lane&15
    int i  = mt * 2 + (q >> 1);
    int d0 = (q & 1) * 4;
    int o  = lane & 15;
    int iw = mt * 2 + (lane >> 5);
    {
        const float4 w4 = *(const float4*)(W + ((((size_t)i * J_ + j0) * DOUT_ + o) * DIN_ + d0));
        float val = acc0[0] * w4.x + acc0[1] * w4.y + acc0[2] * w4.z + acc0[3] * w4.w;
        #pragma unroll
        for (int off = 1; off < 32; off <<= 1)
            val += __shfl_xor(val, off, 32);
        if ((lane & 31) == 0) {
            float* dst = blog + (size_t)iw * J_ + j0;
            if (first) *dst = val; else *dst += val;
        }
    }
    {
        const float4 w4 = *(const float4*)(W + ((((size_t)i * J_ + j1) * DOUT_ + o) * DIN_ + d0));
        float val = acc1[0] * w4.x + acc1[1] * w4.y + acc1[2] * w4.z + acc1[3] * w4.w;
        #pragma unroll
        for (int off = 1; off < 32; off <<= 1)
            val += __shfl_xor(val, off, 32);
        if ((lane & 31) == 0) {
            float* dst = blog + (size_t)iw * J_ + j1;
            if (first) *dst = val; else *dst += val;
        }
    }
}

// ---------------------------------------------------------------------------
extern "C" void kernel_launch(void* const* d_in, const int* in_sizes, int n_in,
                              void* d_out, int out_size, void* d_ws, size_t ws_size,
                              hipStream_t stream)
{
    const float* x = (const float*)d_in[0];   // [B, I, DIN]
    const float* W = (const float*)d_in[1];   // [I, J, DOUT, DIN]
    float* s_out = (float*)d_out;             // [B, J, DOUT]

    char* ws = (char*)d_ws;
    ushort_t* Sbt_hi = (ushort_t*)(ws);                    // 81,920 B
    ushort_t* Sbt_lo = (ushort_t*)(ws + 81920);            // 81,920 B
    float*    blog   = (float*)   (ws + 163840);           // 46,080 B  (~210 KB)

    for (int it = 0; it < 3; ++it) {
        gemm_s_fused_kernel<<<160, 1024, 0, stream>>>(x, W, blog, s_out,
                                                      Sbt_hi, Sbt_lo, it);
        if (it < 2)
            gemm_bupd_kernel<<<720, 256, 0, stream>>>(x, Sbt_hi, Sbt_lo,
                                                      W, blog, it == 0 ? 1 : 0);
    }
}